// Round 8
// baseline (1346.276 us; speedup 1.0000x reference)
//
#include <hip/hip_runtime.h>

#define D     200
#define H     4
#define DH    50
#define NE    38
#define NTY   4
#define NC    608      // edge combos = 38*4*4
#define NCT   612      // + 4 self combos
#define BG    256      // graphs
#define LG    1024     // edges per graph
#define EE    262144   // E
#define NN    51200    // N
#define EA    313344   // E + N

#define NTILES 13      // ceil(200/16)
#define KSTEPS 7       // ceil(200/32)
#define NG     25      // 200/8 real k-groups (no padding in LDS)

typedef __attribute__((ext_vector_type(4))) float  f32x4;
typedef __attribute__((ext_vector_type(8))) short  bf16x8;

__device__ __forceinline__ short bf_hi(float f) {
    unsigned u = __float_as_uint(f);
    unsigned r = u + 0x7fffu + ((u >> 16) & 1u);
    return (short)(r >> 16);
}
__device__ __forceinline__ float bf_f(short s) {
    return __uint_as_float(((unsigned)(unsigned short)s) << 16);
}

// ---------------- histogram / combo / degrees / per-graph combo hist ----------------
__global__ __launch_bounds__(256) void k_hist(const int* __restrict__ ei, const int* __restrict__ et,
                                              const int* __restrict__ nt, int* hist, int* outdeg, int* indeg,
                                              int* hcnt) {
    int e = blockIdx.x * 256 + threadIdx.x;
    if (e >= EE) return;
    int s = ei[e], d = ei[EE + e];
    int c = et[e] * 16 + nt[s] * 4 + nt[d];
    atomicAdd(&hist[c], 1);
    atomicAdd(&outdeg[s], 1);
    atomicAdd(&indeg[d], 1);
    atomicAdd(&hcnt[(e >> 10) * NC + c], 1);
}

// per-block LDS reduction -> 4 global atomics per block
__global__ __launch_bounds__(256) void k_ntcnt(const int* __restrict__ nt, int* ntcnt) {
    __shared__ int loc[NTY];
    int t = threadIdx.x;
    if (t < NTY) loc[t] = 0;
    __syncthreads();
    int n = blockIdx.x * 256 + t;
    if (n < NN) atomicAdd(&loc[nt[n]], 1);
    __syncthreads();
    if (t < NTY) atomicAdd(&ntcnt[t], loc[t]);
}

__global__ void k_tcnt(const int* __restrict__ hist, int* tcnt) {
    int t = threadIdx.x;
    if (t < NE) { int s = 0; for (int i = 0; i < 16; i++) s += hist[t*16 + i]; tcnt[t] = s; }
}

// ---------------- per-(node,type) signed coefficients ----------------
__global__ __launch_bounds__(256) void k_coef(const int* __restrict__ ei, const int* __restrict__ et,
                                              float* coef) {
    int e = blockIdx.x * 256 + threadIdx.x;
    if (e >= EE) return;
    int s = ei[e], d = ei[EE + e], t = et[e];
    unsafeAtomicAdd(&coef[(size_t)d * NE + t],  1.f);
    unsafeAtomicAdd(&coef[(size_t)s * NE + t], -1.f);
}

// sums = coef^T (38 x NN) @ x (NN x 200), K-split GEMM.
__global__ __launch_bounds__(256) void k_xfsum3(const float* __restrict__ x, const float* __restrict__ coef,
                                                float* sums) {
    const int CH = NN / 256;   // 200 nodes per block
    int t = threadIdx.x;
    int n0 = blockIdx.x * CH;
    float acc[NE];
    #pragma unroll
    for (int m = 0; m < NE; m++) acc[m] = 0.f;
    if (t < D) {
        for (int k = 0; k < CH; k++) {
            int n = n0 + k;
            float xv = x[(size_t)n * D + t];
            const float* cf = coef + (size_t)n * NE;
            #pragma unroll
            for (int m = 0; m < NE; m++) acc[m] += cf[m] * xv;
        }
        #pragma unroll
        for (int m = 0; m < NE; m++)
            if (acc[m] != 0.f) unsafeAtomicAdd(&sums[m * D + t], acc[m]);
    }
}

// ---------------- CSR build: scan + scatter ----------------
__global__ __launch_bounds__(256) void k_scan(const int* __restrict__ a, const int* __restrict__ b,
                                              int* aoff, int* boff, int* acur, int* bcur) {
    __shared__ int pa[256], pb[256];
    int t = threadIdx.x;
    const int CH = NN / 256;   // 200
    int base = t * CH;
    int s0 = 0, s1 = 0;
    for (int i = 0; i < CH; i++) { s0 += a[base + i]; s1 += b[base + i]; }
    pa[t] = s0; pb[t] = s1; __syncthreads();
    for (int off = 1; off < 256; off <<= 1) {
        int va = (t >= off) ? pa[t - off] : 0;
        int vb = (t >= off) ? pb[t - off] : 0;
        __syncthreads();
        pa[t] += va; pb[t] += vb;
        __syncthreads();
    }
    int ra = pa[t] - s0, rb = pb[t] - s1;
    for (int i = 0; i < CH; i++) {
        aoff[base + i] = ra; acur[base + i] = ra; ra += a[base + i];
        boff[base + i] = rb; bcur[base + i] = rb; rb += b[base + i];
    }
    if (t == 255) { aoff[NN] = ra; boff[NN] = rb; }
}

__global__ __launch_bounds__(256) void k_scatter(const int* __restrict__ ei, int* scur, int* dcur,
                                                 int* slist, int* dlist) {
    int e = blockIdx.x * 256 + threadIdx.x;
    if (e >= EE) return;
    int s = ei[e], d = ei[EE + e];
    slist[atomicAdd(&scur[s], 1)] = e;
    dlist[atomicAdd(&dcur[d], 1)] = e;
}

// ---------------- per-combo MLP pipeline ----------------
__global__ __launch_bounds__(256) void k_combos1(const float* __restrict__ We1, const float* __restrict__ be1,
                                                 const int* __restrict__ hist, const int* __restrict__ ntcnt,
                                                 float* __restrict__ h1, float* bn1) {
    int c = blockIdx.x, d = threadIdx.x;
    if (d >= D) return;
    float v, w;
    if (c < NC) {
        int etp = c >> 4, ts = (c >> 2) & 3, td = c & 3;
        v = We1[etp*D + d] + We1[(39+ts)*D + d] + We1[(43+td)*D + d] + be1[d];
        w = (float)hist[c];
    } else {
        int t = c - NC;
        v = We1[38*D + d] + We1[(39+t)*D + d] + We1[(43+t)*D + d] + be1[d];
        w = (float)ntcnt[t];
    }
    h1[c*D + d] = v;
    unsafeAtomicAdd(&bn1[d], w * v);
    unsafeAtomicAdd(&bn1[D + d], w * v * v);
}

__global__ __launch_bounds__(256) void k_combos2(const float* __restrict__ h1, const float* __restrict__ bn1,
                                                 const float* __restrict__ ge1, const float* __restrict__ bte1,
                                                 const float* __restrict__ We2, const float* __restrict__ be2,
                                                 float* __restrict__ embE, float* __restrict__ embS) {
    __shared__ float v[D];
    int c = blockIdx.x, t = threadIdx.x;
    if (t < D) {
        float cnt = (float)(EE + NN);
        float m = bn1[t] / cnt;
        float var = bn1[D + t] / cnt - m * m;
        float r = rsqrtf(var + 1e-5f);
        float u = (h1[c*D + t] - m) * r * ge1[t] + bte1[t];
        v[t] = fmaxf(u, 0.f);
    }
    __syncthreads();
    if (t < D) {
        float acc = be2[t];
        for (int k = 0; k < D; k++) acc += v[k] * We2[k*D + t];
        if (c < NC) embE[c*D + t] = acc; else embS[(c-NC)*D + t] = acc;
    }
}

__global__ __launch_bounds__(256) void k_combos3(const float* __restrict__ embE, const float* __restrict__ sumsxf,
                                                 const int* __restrict__ tcnt, const float* __restrict__ Wa1,
                                                 const float* __restrict__ ba1, const int* __restrict__ hist,
                                                 float* __restrict__ h2, float* bn2) {
    __shared__ float a[2*D];
    int c = blockIdx.x, t = threadIdx.x;
    int etp = c >> 4;
    if (t < D) {
        a[t] = embE[c*D + t];
        float cn = fmaxf((float)tcnt[etp], 1.f);
        a[D + t] = sumsxf[etp*D + t] / cn;
    }
    __syncthreads();
    if (t < D) {
        float acc = ba1[t];
        for (int k = 0; k < 2*D; k++) acc += a[k] * Wa1[k*D + t];
        h2[c*D + t] = acc;
        float w = (float)hist[c];
        unsafeAtomicAdd(&bn2[t], w * acc);
        unsafeAtomicAdd(&bn2[D + t], w * acc * acc);
    }
}

// also writes RcT (200 x 608) for the coalesced attention score pass
__global__ __launch_bounds__(256) void k_combos4(const float* __restrict__ h2, const float* __restrict__ bn2,
                                                 const float* __restrict__ ga1, const float* __restrict__ bta1,
                                                 const float* __restrict__ Wa2, const float* __restrict__ ba2,
                                                 float* __restrict__ Rc, float* __restrict__ RcT) {
    __shared__ float v[D];
    int c = blockIdx.x, t = threadIdx.x;
    if (t < D) {
        float inv = 1.f / (float)EE;
        float m = bn2[t] * inv;
        float var = bn2[D + t] * inv - m * m;
        float r = rsqrtf(var + 1e-5f);
        float u = (h2[c*D + t] - m) * r * ga1[t] + bta1[t];
        v[t] = fmaxf(u, 0.f);
    }
    __syncthreads();
    if (t < D) {
        float acc = ba2[t];
        for (int k = 0; k < D; k++) acc += v[k] * Wa2[k*D + t];
        Rc[c*D + t] = acc;
        RcT[(size_t)t * NC + c] = acc;
    }
}

// ---------------- per-graph attention, combo space, MLP-friendly layout ----------------
__global__ __launch_bounds__(256) void k_attn(const float* __restrict__ sent, const float* __restrict__ Watt,
                                              const float* __restrict__ Rc, const float* __restrict__ RcT,
                                              const int* __restrict__ hcnt, float* __restrict__ upd) {
    __shared__ float q[D];
    __shared__ float w[NC];
    __shared__ float red[8];
    __shared__ float part[4][D];
    int b = blockIdx.x, t = threadIdx.x;
    int wave = t >> 6, lane = t & 63;
    if (t < D) {
        float acc = 0.f;
        for (int k = 0; k < D; k++) acc += sent[b*D + k] * Watt[k*D + t];
        q[t] = acc;
    }
    __syncthreads();
    const float scl = 0.07071067811865475f;   // 1/sqrt(200)
    {
        float s0 = 0.f, s1 = 0.f, s2 = 0.f;
        for (int k = 0; k < D; k++) {
            float qk = q[k];
            const float* row = RcT + (size_t)k * NC;
            s0 += qk * row[t];
            s1 += qk * row[t + 256];
            if (t < NC - 512) s2 += qk * row[t + 512];
        }
        w[t] = s0 * scl;
        w[t + 256] = s1 * scl;
        if (t < NC - 512) w[t + 512] = s2 * scl;
    }
    __syncthreads();
    float mx = -1e30f;
    for (int c = t; c < NC; c += 256) mx = fmaxf(mx, w[c]);
    for (int o = 32; o; o >>= 1) mx = fmaxf(mx, __shfl_xor(mx, o));
    if (lane == 0) red[wave] = mx;
    __syncthreads();
    mx = fmaxf(fmaxf(red[0], red[1]), fmaxf(red[2], red[3]));
    float sm = 0.f;
    for (int c = t; c < NC; c += 256) {
        float wv = (float)hcnt[b * NC + c] * __expf(w[c] - mx);
        w[c] = wv;
        sm += wv;
    }
    for (int o = 32; o; o >>= 1) sm += __shfl_xor(sm, o);
    if (lane == 0) red[4 + wave] = sm;
    __syncthreads();
    float inv = 1.f / (red[4] + red[5] + red[6] + red[7]);
    float a4[4] = {0.f, 0.f, 0.f, 0.f};
    for (int c = wave * (NC/4); c < (wave + 1) * (NC/4); c++) {
        float wv = w[c];
        const float* r = Rc + c * D;
        #pragma unroll
        for (int j = 0; j < 4; j++) { int dd = lane + 64*j; if (dd < D) a4[j] += wv * r[dd]; }
    }
    #pragma unroll
    for (int j = 0; j < 4; j++) { int dd = lane + 64*j; if (dd < D) part[wave][dd] = a4[j]; }
    __syncthreads();
    if (t < D) upd[b*D + t] = (part[0][t] + part[1][t] + part[2][t] + part[3][t]) * inv;
}

// ---------------- GK/GM (per graph) and SK/SM (per node type) ----------------
__global__ __launch_bounds__(256) void k_gkgm(const float* __restrict__ upd, const float* __restrict__ embS,
                                              const float* __restrict__ Wk, const float* __restrict__ bk,
                                              const float* __restrict__ Wm, const float* __restrict__ bm,
                                              float* GK, float* GM, float* SK, float* SM) {
    __shared__ float v[D];
    int bI = blockIdx.x, t = threadIdx.x;
    const float* in = (bI < BG) ? (upd + bI*D) : (embS + (bI - BG)*D);
    if (t < D) v[t] = in[t];
    __syncthreads();
    if (t < D) {
        float a1 = bk[t], a2 = bm[t];
        for (int k = 0; k < D; k++) {
            a1 += v[k] * Wk[(D + k)*D + t];
            a2 += v[k] * Wm[(D + k)*D + t];
        }
        if (bI < BG) { GK[bI*D + t] = a1; GM[bI*D + t] = a2; }
        else         { SK[(bI-BG)*D + t] = a1; SM[(bI-BG)*D + t] = a2; }
    }
}

// ---------------- weight packing: B-fragment order, bf16 hi/lo ----------------
__global__ __launch_bounds__(256) void k_packW(const float* __restrict__ Wk, const float* __restrict__ Wm,
                                               const float* __restrict__ Wq, const float* __restrict__ Wo1,
                                               const float* __restrict__ Wo2, short* __restrict__ Bpk) {
    int blk = blockIdx.x;                    // mat*91 + nt*7 + ks
    int mat = blk / (NTILES * KSTEPS);
    int rem = blk - mat * (NTILES * KSTEPS);
    int nt = rem / KSTEPS, ks = rem - nt * KSTEPS;
    const float* W = (mat == 0) ? Wk : (mat == 1) ? Wm : (mat == 2) ? Wq : (mat == 3) ? Wo1 : Wo2;
    int t = threadIdx.x;
    for (int idx = t; idx < 1024; idx += 256) {
        int split = idx >> 9;
        int lane = (idx & 511) >> 3;
        int j = idx & 7;
        int n = nt * 16 + (lane & 15);
        int k = ks * 32 + ((lane >> 4) << 3) + j;
        float v = (k < D && n < D) ? W[k * D + n] : 0.f;
        short h = bf_hi(v);
        short out = split ? bf_hi(v - bf_f(h)) : h;
        Bpk[(size_t)blk * 1024 + idx] = out;
    }
}

// ---------------- MFMA GEMM core helpers (v2: compact LDS, XOR swizzle) ----------------
// A in LDS: [strip 4][g 25][split 2][lanem 16 (^= g&15)] x bf16x8 = 51200 B exactly.
__device__ __forceinline__ void stage_A(const float* __restrict__ A, int n0, short* Apk,
                                        int preop, const float* scl, const float* sft) {
    int t = threadIdx.x;
    bf16x8* Apk8 = (bf16x8*)Apk;
    for (int f = t; f < 64 * NG; f += 256) {
        int r = f / NG, g = f - NG * r;
        const float* src = A + (size_t)(n0 + r) * D + g * 8;
        float v[8];
        float4 p0 = *(const float4*)src;
        float4 p1 = *(const float4*)(src + 4);
        v[0]=p0.x; v[1]=p0.y; v[2]=p0.z; v[3]=p0.w;
        v[4]=p1.x; v[5]=p1.y; v[6]=p1.z; v[7]=p1.w;
        if (preop) {
            #pragma unroll
            for (int j = 0; j < 8; j++) v[j] = fmaxf(v[j] * scl[g*8+j] + sft[g*8+j], 0.f);
        }
        bf16x8 hi, lo;
        #pragma unroll
        for (int j = 0; j < 8; j++) {
            short h = bf_hi(v[j]);
            hi[j] = h;
            lo[j] = bf_hi(v[j] - bf_f(h));
        }
        int strip = r >> 4;
        int sw = (r & 15) ^ (g & 15);          // bank swizzle
        int base = (strip * NG + g) * 2;
        Apk8[(base + 0) * 16 + sw] = hi;
        Apk8[(base + 1) * 16 + sw] = lo;
    }
}

__device__ __forceinline__ void mfma_strip(const short* Apk, const short* Bmat, int w, int lane,
                                           f32x4 acc[NTILES]) {
    const bf16x8* Apk8 = (const bf16x8*)Apk;
    const bf16x8* B8   = (const bf16x8*)Bmat;
    #pragma unroll
    for (int nt = 0; nt < NTILES; nt++) { acc[nt][0]=0.f; acc[nt][1]=0.f; acc[nt][2]=0.f; acc[nt][3]=0.f; }
    int quad = lane >> 4, lanem = lane & 15;
    bf16x8 zz;
    #pragma unroll
    for (int j = 0; j < 8; j++) zz[j] = 0;
    for (int ks = 0; ks < KSTEPS; ks++) {
        int g = ks * 4 + quad;                 // 0..27; >=25 is K-padding
        bf16x8 ah = zz, al = zz;
        if (g < NG) {
            int sw = lanem ^ (g & 15);
            int base = (w * NG + g) * 2;
            ah = Apk8[(base + 0) * 16 + sw];
            al = Apk8[(base + 1) * 16 + sw];
        }
        #pragma unroll
        for (int nt = 0; nt < NTILES; nt++) {
            bf16x8 bh = B8[((nt * KSTEPS + ks) * 2 + 0) * 64 + lane];
            bf16x8 bl = B8[((nt * KSTEPS + ks) * 2 + 1) * 64 + lane];
            acc[nt] = __builtin_amdgcn_mfma_f32_16x16x32_bf16(al, bh, acc[nt], 0, 0, 0);
            acc[nt] = __builtin_amdgcn_mfma_f32_16x16x32_bf16(ah, bl, acc[nt], 0, 0, 0);
            acc[nt] = __builtin_amdgcn_mfma_f32_16x16x32_bf16(ah, bh, acc[nt], 0, 0, 0);
        }
    }
}

__device__ __forceinline__ void store_C(f32x4 acc[NTILES], float* __restrict__ C, int n0, int w, int lane,
                                        const float* __restrict__ bias, float postscale) {
    int colb = lane & 15, quad = lane >> 4;
    #pragma unroll
    for (int nt = 0; nt < NTILES; nt++) {
        int col = nt * 16 + colb;
        if (col < D) {
            float bj = bias ? bias[col] : 0.f;
            #pragma unroll
            for (int r = 0; r < 4; r++) {
                int row = n0 + w * 16 + quad * 4 + r;
                C[(size_t)row * D + col] = (acc[nt][r] + bj) * postscale;
            }
        }
    }
}

// ---------------- fused x @ {Wk[:D], Wm[:D], Wq}  (MFMA) ----------------
__global__ __launch_bounds__(256, 4) void k_mmf3(const float* __restrict__ A, const short* __restrict__ Bpk,
                                                 const float* __restrict__ bq,
                                                 float* __restrict__ XK, float* __restrict__ XM, float* __restrict__ XQ) {
    __shared__ short Apk[4 * NG * 2 * 16 * 8];   // 51200 B -> 3 blocks/CU
    int n0 = blockIdx.x * 64;
    stage_A(A, n0, Apk, 0, nullptr, nullptr);
    __syncthreads();
    int w = threadIdx.x >> 6, lane = threadIdx.x & 63;
    f32x4 acc[NTILES];
    const int matstride = NTILES * KSTEPS * 1024;   // shorts per mat = 91*1024
    mfma_strip(Apk, Bpk + 0 * matstride, w, lane, acc);
    store_C(acc, XK, n0, w, lane, nullptr, 1.f);
    mfma_strip(Apk, Bpk + 1 * matstride, w, lane, acc);
    store_C(acc, XM, n0, w, lane, nullptr, 1.f);
    mfma_strip(Apk, Bpk + 2 * matstride, w, lane, acc);
    store_C(acc, XQ, n0, w, lane, bq, 0.14142135623730950488f);
}

// ---------------- generic MFMA matmul (one B), optional BN+relu preop ----------------
__global__ __launch_bounds__(256, 4) void k_mmf(const float* __restrict__ A, const short* __restrict__ Bmat,
                                                const float* __restrict__ bias, float* __restrict__ C,
                                                int preop, const float* __restrict__ bnacc, float invCnt,
                                                const float* __restrict__ g, const float* __restrict__ bb,
                                                float postscale) {
    __shared__ short Apk[4 * NG * 2 * 16 * 8];
    __shared__ float scl[D], sft[D];
    int t = threadIdx.x;
    int n0 = blockIdx.x * 64;
    if (preop) {
        if (t < D) {
            float m = bnacc[t] * invCnt;
            float var = bnacc[D + t] * invCnt - m * m;
            float rs = rsqrtf(var + 1e-5f);
            float s = rs * g[t];
            scl[t] = s;
            sft[t] = bb[t] - m * s;
        }
        __syncthreads();
    }
    stage_A(A, n0, Apk, preop, scl, sft);
    __syncthreads();
    int w = t >> 6, lane = t & 63;
    f32x4 acc[NTILES];
    mfma_strip(Apk, Bmat, w, lane, acc);
    store_C(acc, C, n0, w, lane, bias, postscale);
}

// ---------------- edge softmax, src-CSR, wave per node, no atomics ----------------
__global__ __launch_bounds__(256) void k_soft(const int* __restrict__ ei, const int* __restrict__ nt,
                                              const int* __restrict__ soff, const int* __restrict__ slist,
                                              const int* __restrict__ outdeg,
                                              const float* __restrict__ XQ, const float* __restrict__ XK,
                                              const float* __restrict__ GK, const float* __restrict__ SK,
                                              float* __restrict__ sc, float* __restrict__ scale) {
    int wave = threadIdx.x >> 6, lane = threadIdx.x & 63;
    int n = blockIdx.x * 4 + wave;
    if (n >= NN) return;
    float qv[4];
    #pragma unroll
    for (int j = 0; j < 4; j++) { int dd = lane + 64*j; qv[j] = (dd < D) ? XQ[(size_t)n*D + dd] : 0.f; }
    float den0 = 0.f, den1 = 0.f, den2 = 0.f, den3 = 0.f;
    {
        int tn = nt[n];
        float h0 = 0, h1 = 0, h2 = 0, h3 = 0;
        #pragma unroll
        for (int j = 0; j < 4; j++) {
            int dd = lane + 64*j;
            if (dd < D) {
                float p = qv[j] * (XK[(size_t)n*D + dd] + SK[tn*D + dd]);
                int hh = dd / DH;
                if (hh == 0) h0 += p; else if (hh == 1) h1 += p; else if (hh == 2) h2 += p; else h3 += p;
            }
        }
        for (int o = 32; o; o >>= 1) {
            h0 += __shfl_xor(h0, o); h1 += __shfl_xor(h1, o);
            h2 += __shfl_xor(h2, o); h3 += __shfl_xor(h3, o);
        }
        float e0 = __expf(h0), e1 = __expf(h1), e2 = __expf(h2), e3 = __expf(h3);
        den0 += e0; den1 += e1; den2 += e2; den3 += e3;
        if (lane < 4) {
            float v = (lane == 0) ? e0 : (lane == 1) ? e1 : (lane == 2) ? e2 : e3;
            sc[(size_t)(EE + n) * 4 + lane] = v;
        }
    }
    int beg = soff[n], end = soff[n + 1];
    for (int i = beg; i < end; i++) {
        int e = slist[i];
        int tail = ei[EE + e];
        int g = e >> 10;
        float h0 = 0, h1 = 0, h2 = 0, h3 = 0;
        #pragma unroll
        for (int j = 0; j < 4; j++) {
            int dd = lane + 64*j;
            if (dd < D) {
                float p = qv[j] * (XK[(size_t)tail*D + dd] + GK[g*D + dd]);
                int hh = dd / DH;
                if (hh == 0) h0 += p; else if (hh == 1) h1 += p; else if (hh == 2) h2 += p; else h3 += p;
            }
        }
        for (int o = 32; o; o >>= 1) {
            h0 += __shfl_xor(h0, o); h1 += __shfl_xor(h1, o);
            h2 += __shfl_xor(h2, o); h3 += __shfl_xor(h3, o);
        }
        float e0 = __expf(h0), e1 = __expf(h1), e2 = __expf(h2), e3 = __expf(h3);
        den0 += e0; den1 += e1; den2 += e2; den3 += e3;
        if (lane < 4) {
            float v = (lane == 0) ? e0 : (lane == 1) ? e1 : (lane == 2) ? e2 : e3;
            sc[(size_t)e * 4 + lane] = v;
        }
    }
    float cnt = (float)(outdeg[n] + 1);
    if (lane < 4) {
        float dn = (lane == 0) ? den0 : (lane == 1) ? den1 : (lane == 2) ? den2 : den3;
        scale[(size_t)n * 4 + lane] = cnt / dn;
    }
}

// ---------------- aggregation, dst-CSR, wave per node, no atomics ----------------
__global__ __launch_bounds__(256) void k_aggr(const int* __restrict__ ei, const int* __restrict__ nt,
                                              const int* __restrict__ doff, const int* __restrict__ dlist,
                                              const float* __restrict__ sc, const float* __restrict__ scale,
                                              const float* __restrict__ XM, const float* __restrict__ GM,
                                              const float* __restrict__ SM, float* __restrict__ aggr) {
    int wave = threadIdx.x >> 6, lane = threadIdx.x & 63;
    int n = blockIdx.x * 4 + wave;
    if (n >= NN) return;
    float acc[4] = {0.f, 0.f, 0.f, 0.f};
    {
        int tn = nt[n];
        float4 ss = *(const float4*)&sc[(size_t)(EE + n) * 4];
        float4 sl = *(const float4*)&scale[(size_t)n * 4];
        float a0 = ss.x * sl.x, a1 = ss.y * sl.y, a2 = ss.z * sl.z, a3 = ss.w * sl.w;
        #pragma unroll
        for (int j = 0; j < 4; j++) {
            int dd = lane + 64*j;
            if (dd < D) {
                float al = (dd < DH) ? a0 : (dd < 2*DH) ? a1 : (dd < 3*DH) ? a2 : a3;
                acc[j] += al * (XM[(size_t)n*D + dd] + SM[tn*D + dd]);
            }
        }
    }
    int beg = doff[n], end = doff[n + 1];
    for (int i = beg; i < end; i++) {
        int e = dlist[i];
        int s = ei[e];
        int g = e >> 10;
        float4 ss = *(const float4*)&sc[(size_t)e * 4];
        float4 sl = *(const float4*)&scale[(size_t)s * 4];
        float a0 = ss.x * sl.x, a1 = ss.y * sl.y, a2 = ss.z * sl.z, a3 = ss.w * sl.w;
        #pragma unroll
        for (int j = 0; j < 4; j++) {
            int dd = lane + 64*j;
            if (dd < D) {
                float al = (dd < DH) ? a0 : (dd < 2*DH) ? a1 : (dd < 3*DH) ? a2 : a3;
                acc[j] += al * (XM[(size_t)s*D + dd] + GM[g*D + dd]);
            }
        }
    }
    #pragma unroll
    for (int j = 0; j < 4; j++) {
        int dd = lane + 64*j;
        if (dd < D) aggr[(size_t)n*D + dd] = acc[j];
    }
}

// ---------------- column stats for final BN ----------------
__global__ __launch_bounds__(256) void k_colstats(const float* __restrict__ T1, float* bn3) {
    int t = threadIdx.x;
    if (t >= D) return;
    int r0 = blockIdx.x * 256;
    float s = 0.f, q = 0.f;
    for (int r = r0; r < r0 + 256; r++) {
        float v = T1[(size_t)r * D + t];
        s += v; q += v * v;
    }
    unsafeAtomicAdd(&bn3[t], s);
    unsafeAtomicAdd(&bn3[D + t], q);
}

extern "C" void kernel_launch(void* const* d_in, const int* in_sizes, int n_in,
                              void* d_out, int out_size, void* d_ws, size_t ws_size,
                              hipStream_t stream) {
    const float* x    = (const float*)d_in[0];
    const float* sent = (const float*)d_in[2];
    const float* We1  = (const float*)d_in[3];
    const float* be1  = (const float*)d_in[4];
    const float* ge1  = (const float*)d_in[5];
    const float* bte1 = (const float*)d_in[6];
    const float* We2  = (const float*)d_in[7];
    const float* be2  = (const float*)d_in[8];
    const float* Wa1  = (const float*)d_in[9];
    const float* ba1  = (const float*)d_in[10];
    const float* ga1  = (const float*)d_in[11];
    const float* bta1 = (const float*)d_in[12];
    const float* Wa2  = (const float*)d_in[13];
    const float* ba2  = (const float*)d_in[14];
    const float* Watt = (const float*)d_in[15];
    const float* Wk   = (const float*)d_in[16];
    const float* bk   = (const float*)d_in[17];
    const float* Wm   = (const float*)d_in[18];
    const float* bm   = (const float*)d_in[19];
    const float* Wq   = (const float*)d_in[20];
    const float* bq   = (const float*)d_in[21];
    const float* Wo1  = (const float*)d_in[22];
    const float* bo1  = (const float*)d_in[23];
    const float* go1  = (const float*)d_in[24];
    const float* bto1 = (const float*)d_in[25];
    const float* Wo2  = (const float*)d_in[26];
    const float* bo2  = (const float*)d_in[27];
    const int* ei = (const int*)d_in[28];
    const int* et = (const int*)d_in[29];
    const int* nt = (const int*)d_in[30];

    char* ws = (char*)d_ws;
    size_t off = 0;
    auto alloc = [&](size_t bytes) -> char* {
        char* p = ws + off;
        off = (off + bytes + 255) & ~(size_t)255;
        return p;
    };
    // ---- zeroed region ----
    int*   hist   = (int*)  alloc(NC * 4);
    int*   ntcnt  = (int*)  alloc(NTY * 4);
    float* bn1    = (float*)alloc(2 * D * 4);
    float* bn2    = (float*)alloc(2 * D * 4);
    float* bn3    = (float*)alloc(2 * D * 4);
    float* sumsxf = (float*)alloc(NE * D * 4);
    int*   outdeg = (int*)  alloc(NN * 4);
    int*   indeg  = (int*)  alloc(NN * 4);
    int*   hcnt   = (int*)  alloc((size_t)BG * NC * 4);   // per-graph combo histogram
    size_t zero_end = off;
    // ---- rest ----
    int* tcnt = (int*)alloc(NE * 4);
    int* soff_ = (int*)alloc((NN + 1) * 4);
    int* doff_ = (int*)alloc((NN + 1) * 4);
    int* scur = (int*)alloc(NN * 4);
    int* dcur = (int*)alloc(NN * 4);
    int* slist = (int*)alloc((size_t)EE * 4);
    int* dlist = (int*)alloc((size_t)EE * 4);
    short* Bpk  = (short*)alloc((size_t)5 * NTILES * KSTEPS * 1024 * 2);   // 5 mats, bf16 hi/lo packed
    float* h1v   = (float*)alloc((size_t)NCT * D * 4);
    float* embE  = (float*)alloc((size_t)NC * D * 4);
    float* embS  = (float*)alloc((size_t)NTY * D * 4);
    float* h2pre = (float*)alloc((size_t)NC * D * 4);
    float* Rc    = (float*)alloc((size_t)NC * D * 4);
    float* RcT   = (float*)alloc((size_t)D * NC * 4);
    float* upd   = (float*)alloc((size_t)BG * D * 4);
    float* GK    = (float*)alloc((size_t)BG * D * 4);
    float* GM    = (float*)alloc((size_t)BG * D * 4);
    float* SK    = (float*)alloc((size_t)NTY * D * 4);
    float* SM    = (float*)alloc((size_t)NTY * D * 4);
    float* sc    = (float*)alloc((size_t)EA * H * 4);
    float* XK    = (float*)alloc((size_t)NN * D * 4);
    float* XM    = (float*)alloc((size_t)NN * D * 4);
    float* XQ    = (float*)alloc((size_t)NN * D * 4);
    // aliases (liveness-checked):
    float* coef  = XK;            // dead before k_mmf3 writes XK
    float* scale = h1v;           // h1v dead before k_soft writes scale
    float* aggr  = XQ;            // XQ dead after k_soft
    float* T1    = XK;            // XK dead after k_soft

    const int matstride = NTILES * KSTEPS * 1024;   // shorts per packed mat

    hipMemsetAsync(ws, 0, zero_end, stream);
    hipMemsetAsync(coef, 0, (size_t)NN * NE * 4, stream);

    k_packW  <<<5 * NTILES * KSTEPS, 256, 0, stream>>>(Wk, Wm, Wq, Wo1, Wo2, Bpk);
    k_hist   <<<EE / 256, 256, 0, stream>>>(ei, et, nt, hist, outdeg, indeg, hcnt);
    k_ntcnt  <<<NN / 256, 256, 0, stream>>>(nt, ntcnt);
    k_coef   <<<EE / 256, 256, 0, stream>>>(ei, et, coef);
    k_tcnt   <<<1, 64, 0, stream>>>(hist, tcnt);
    k_scan   <<<1, 256, 0, stream>>>(outdeg, indeg, soff_, doff_, scur, dcur);
    k_scatter<<<EE / 256, 256, 0, stream>>>(ei, scur, dcur, slist, dlist);
    k_xfsum3 <<<256, 256, 0, stream>>>(x, coef, sumsxf);
    k_combos1<<<NCT, 256, 0, stream>>>(We1, be1, hist, ntcnt, h1v, bn1);
    k_combos2<<<NCT, 256, 0, stream>>>(h1v, bn1, ge1, bte1, We2, be2, embE, embS);
    k_combos3<<<NC, 256, 0, stream>>>(embE, sumsxf, tcnt, Wa1, ba1, hist, h2pre, bn2);
    k_combos4<<<NC, 256, 0, stream>>>(h2pre, bn2, ga1, bta1, Wa2, ba2, Rc, RcT);
    k_attn   <<<BG, 256, 0, stream>>>(sent, Watt, Rc, RcT, hcnt, upd);
    k_gkgm   <<<BG + NTY, 256, 0, stream>>>(upd, embS, Wk, bk, Wm, bm, GK, GM, SK, SM);
    k_mmf3   <<<NN / 64, 256, 0, stream>>>(x, Bpk, bq, XK, XM, XQ);
    k_soft   <<<NN / 4, 256, 0, stream>>>(ei, nt, soff_, slist, outdeg, XQ, XK, GK, SK, sc, scale);
    k_aggr   <<<NN / 4, 256, 0, stream>>>(ei, nt, doff_, dlist, sc, scale, XM, GM, SM, aggr);
    k_mmf    <<<NN / 64, 256, 0, stream>>>(aggr, Bpk + (size_t)3 * matstride, bo1, T1,
                                           0, nullptr, 0.f, nullptr, nullptr, 1.f);
    k_colstats<<<NN / 256, 256, 0, stream>>>(T1, bn3);
    k_mmf    <<<NN / 64, 256, 0, stream>>>(T1, Bpk + (size_t)4 * matstride, bo2, (float*)d_out,
                                           1, bn3, 1.f / (float)NN, go1, bto1, 1.f);
}

// Round 9
// 1253.914 us; speedup vs baseline: 1.0737x; 1.0737x over previous
//
#include <hip/hip_runtime.h>

#define D     200
#define H     4
#define DH    50
#define NE    38
#define NTY   4
#define NC    608      // edge combos = 38*4*4
#define NCT   612      // + 4 self combos
#define BG    256      // graphs
#define LG    1024     // edges per graph
#define EE    262144   // E
#define NN    51200    // N
#define EA    313344   // E + N

#define NTILES 13      // ceil(200/16)
#define KSTEPS 7       // ceil(200/32)
#define NG     25      // real k-groups of 8
#define GSLOT  26      // LDS g-slots (25 real + 1 zero block)

typedef __attribute__((ext_vector_type(4))) float  f32x4;
typedef __attribute__((ext_vector_type(8))) short  bf16x8;

__device__ __forceinline__ short bf_hi(float f) {
    unsigned u = __float_as_uint(f);
    unsigned r = u + 0x7fffu + ((u >> 16) & 1u);
    return (short)(r >> 16);
}
__device__ __forceinline__ float bf_f(short s) {
    return __uint_as_float(((unsigned)(unsigned short)s) << 16);
}

// ---------------- histogram / combo / degrees / per-graph combo hist ----------------
__global__ __launch_bounds__(256) void k_hist(const int* __restrict__ ei, const int* __restrict__ et,
                                              const int* __restrict__ nt, int* hist, int* outdeg, int* indeg,
                                              int* hcnt) {
    int e = blockIdx.x * 256 + threadIdx.x;
    if (e >= EE) return;
    int s = ei[e], d = ei[EE + e];
    int c = et[e] * 16 + nt[s] * 4 + nt[d];
    atomicAdd(&hist[c], 1);
    atomicAdd(&outdeg[s], 1);
    atomicAdd(&indeg[d], 1);
    atomicAdd(&hcnt[(e >> 10) * NC + c], 1);
}

// per-block LDS reduction -> 4 global atomics per block
__global__ __launch_bounds__(256) void k_ntcnt(const int* __restrict__ nt, int* ntcnt) {
    __shared__ int loc[NTY];
    int t = threadIdx.x;
    if (t < NTY) loc[t] = 0;
    __syncthreads();
    int n = blockIdx.x * 256 + t;
    if (n < NN) atomicAdd(&loc[nt[n]], 1);
    __syncthreads();
    if (t < NTY) atomicAdd(&ntcnt[t], loc[t]);
}

__global__ void k_tcnt(const int* __restrict__ hist, int* tcnt) {
    int t = threadIdx.x;
    if (t < NE) { int s = 0; for (int i = 0; i < 16; i++) s += hist[t*16 + i]; tcnt[t] = s; }
}

// ---------------- per-(node,type) signed coefficients ----------------
__global__ __launch_bounds__(256) void k_coef(const int* __restrict__ ei, const int* __restrict__ et,
                                              float* coef) {
    int e = blockIdx.x * 256 + threadIdx.x;
    if (e >= EE) return;
    int s = ei[e], d = ei[EE + e], t = et[e];
    unsafeAtomicAdd(&coef[(size_t)d * NE + t],  1.f);
    unsafeAtomicAdd(&coef[(size_t)s * NE + t], -1.f);
}

// sums = coef^T (38 x NN) @ x (NN x 200), K-split GEMM.
__global__ __launch_bounds__(256) void k_xfsum3(const float* __restrict__ x, const float* __restrict__ coef,
                                                float* sums) {
    const int CH = NN / 256;   // 200 nodes per block
    int t = threadIdx.x;
    int n0 = blockIdx.x * CH;
    float acc[NE];
    #pragma unroll
    for (int m = 0; m < NE; m++) acc[m] = 0.f;
    if (t < D) {
        for (int k = 0; k < CH; k++) {
            int n = n0 + k;
            float xv = x[(size_t)n * D + t];
            const float* cf = coef + (size_t)n * NE;
            #pragma unroll
            for (int m = 0; m < NE; m++) acc[m] += cf[m] * xv;
        }
        #pragma unroll
        for (int m = 0; m < NE; m++)
            if (acc[m] != 0.f) unsafeAtomicAdd(&sums[m * D + t], acc[m]);
    }
}

// ---------------- CSR build: scan + scatter ----------------
__global__ __launch_bounds__(256) void k_scan(const int* __restrict__ a, const int* __restrict__ b,
                                              int* aoff, int* boff, int* acur, int* bcur) {
    __shared__ int pa[256], pb[256];
    int t = threadIdx.x;
    const int CH = NN / 256;   // 200
    int base = t * CH;
    int s0 = 0, s1 = 0;
    for (int i = 0; i < CH; i++) { s0 += a[base + i]; s1 += b[base + i]; }
    pa[t] = s0; pb[t] = s1; __syncthreads();
    for (int off = 1; off < 256; off <<= 1) {
        int va = (t >= off) ? pa[t - off] : 0;
        int vb = (t >= off) ? pb[t - off] : 0;
        __syncthreads();
        pa[t] += va; pb[t] += vb;
        __syncthreads();
    }
    int ra = pa[t] - s0, rb = pb[t] - s1;
    for (int i = 0; i < CH; i++) {
        aoff[base + i] = ra; acur[base + i] = ra; ra += a[base + i];
        boff[base + i] = rb; bcur[base + i] = rb; rb += b[base + i];
    }
    if (t == 255) { aoff[NN] = ra; boff[NN] = rb; }
}

__global__ __launch_bounds__(256) void k_scatter(const int* __restrict__ ei, int* scur, int* dcur,
                                                 int* slist, int* dlist) {
    int e = blockIdx.x * 256 + threadIdx.x;
    if (e >= EE) return;
    int s = ei[e], d = ei[EE + e];
    slist[atomicAdd(&scur[s], 1)] = e;
    dlist[atomicAdd(&dcur[d], 1)] = e;
}

// ---------------- per-combo MLP pipeline ----------------
__global__ __launch_bounds__(256) void k_combos1(const float* __restrict__ We1, const float* __restrict__ be1,
                                                 const int* __restrict__ hist, const int* __restrict__ ntcnt,
                                                 float* __restrict__ h1, float* bn1) {
    int c = blockIdx.x, d = threadIdx.x;
    if (d >= D) return;
    float v, w;
    if (c < NC) {
        int etp = c >> 4, ts = (c >> 2) & 3, td = c & 3;
        v = We1[etp*D + d] + We1[(39+ts)*D + d] + We1[(43+td)*D + d] + be1[d];
        w = (float)hist[c];
    } else {
        int t = c - NC;
        v = We1[38*D + d] + We1[(39+t)*D + d] + We1[(43+t)*D + d] + be1[d];
        w = (float)ntcnt[t];
    }
    h1[c*D + d] = v;
    unsafeAtomicAdd(&bn1[d], w * v);
    unsafeAtomicAdd(&bn1[D + d], w * v * v);
}

__global__ __launch_bounds__(256) void k_combos2(const float* __restrict__ h1, const float* __restrict__ bn1,
                                                 const float* __restrict__ ge1, const float* __restrict__ bte1,
                                                 const float* __restrict__ We2, const float* __restrict__ be2,
                                                 float* __restrict__ embE, float* __restrict__ embS) {
    __shared__ float v[D];
    int c = blockIdx.x, t = threadIdx.x;
    if (t < D) {
        float cnt = (float)(EE + NN);
        float m = bn1[t] / cnt;
        float var = bn1[D + t] / cnt - m * m;
        float r = rsqrtf(var + 1e-5f);
        float u = (h1[c*D + t] - m) * r * ge1[t] + bte1[t];
        v[t] = fmaxf(u, 0.f);
    }
    __syncthreads();
    if (t < D) {
        float acc = be2[t];
        for (int k = 0; k < D; k++) acc += v[k] * We2[k*D + t];
        if (c < NC) embE[c*D + t] = acc; else embS[(c-NC)*D + t] = acc;
    }
}

__global__ __launch_bounds__(256) void k_combos3(const float* __restrict__ embE, const float* __restrict__ sumsxf,
                                                 const int* __restrict__ tcnt, const float* __restrict__ Wa1,
                                                 const float* __restrict__ ba1, const int* __restrict__ hist,
                                                 float* __restrict__ h2, float* bn2) {
    __shared__ float a[2*D];
    int c = blockIdx.x, t = threadIdx.x;
    int etp = c >> 4;
    if (t < D) {
        a[t] = embE[c*D + t];
        float cn = fmaxf((float)tcnt[etp], 1.f);
        a[D + t] = sumsxf[etp*D + t] / cn;
    }
    __syncthreads();
    if (t < D) {
        float acc = ba1[t];
        for (int k = 0; k < 2*D; k++) acc += a[k] * Wa1[k*D + t];
        h2[c*D + t] = acc;
        float w = (float)hist[c];
        unsafeAtomicAdd(&bn2[t], w * acc);
        unsafeAtomicAdd(&bn2[D + t], w * acc * acc);
    }
}

// also writes RcT (200 x 608) for the coalesced attention score pass
__global__ __launch_bounds__(256) void k_combos4(const float* __restrict__ h2, const float* __restrict__ bn2,
                                                 const float* __restrict__ ga1, const float* __restrict__ bta1,
                                                 const float* __restrict__ Wa2, const float* __restrict__ ba2,
                                                 float* __restrict__ Rc, float* __restrict__ RcT) {
    __shared__ float v[D];
    int c = blockIdx.x, t = threadIdx.x;
    if (t < D) {
        float inv = 1.f / (float)EE;
        float m = bn2[t] * inv;
        float var = bn2[D + t] * inv - m * m;
        float r = rsqrtf(var + 1e-5f);
        float u = (h2[c*D + t] - m) * r * ga1[t] + bta1[t];
        v[t] = fmaxf(u, 0.f);
    }
    __syncthreads();
    if (t < D) {
        float acc = ba2[t];
        for (int k = 0; k < D; k++) acc += v[k] * Wa2[k*D + t];
        Rc[c*D + t] = acc;
        RcT[(size_t)t * NC + c] = acc;
    }
}

// ---------------- per-graph attention, combo space ----------------
__global__ __launch_bounds__(256) void k_attn(const float* __restrict__ sent, const float* __restrict__ Watt,
                                              const float* __restrict__ Rc, const float* __restrict__ RcT,
                                              const int* __restrict__ hcnt, float* __restrict__ upd) {
    __shared__ float q[D];
    __shared__ float w[NC];
    __shared__ float red[8];
    __shared__ float part[4][D];
    int b = blockIdx.x, t = threadIdx.x;
    int wave = t >> 6, lane = t & 63;
    if (t < D) {
        float acc = 0.f;
        for (int k = 0; k < D; k++) acc += sent[b*D + k] * Watt[k*D + t];
        q[t] = acc;
    }
    __syncthreads();
    const float scl = 0.07071067811865475f;   // 1/sqrt(200)
    {
        float s0 = 0.f, s1 = 0.f, s2 = 0.f;
        for (int k = 0; k < D; k++) {
            float qk = q[k];
            const float* row = RcT + (size_t)k * NC;
            s0 += qk * row[t];
            s1 += qk * row[t + 256];
            if (t < NC - 512) s2 += qk * row[t + 512];
        }
        w[t] = s0 * scl;
        w[t + 256] = s1 * scl;
        if (t < NC - 512) w[t + 512] = s2 * scl;
    }
    __syncthreads();
    float mx = -1e30f;
    for (int c = t; c < NC; c += 256) mx = fmaxf(mx, w[c]);
    for (int o = 32; o; o >>= 1) mx = fmaxf(mx, __shfl_xor(mx, o));
    if (lane == 0) red[wave] = mx;
    __syncthreads();
    mx = fmaxf(fmaxf(red[0], red[1]), fmaxf(red[2], red[3]));
    float sm = 0.f;
    for (int c = t; c < NC; c += 256) {
        float wv = (float)hcnt[b * NC + c] * __expf(w[c] - mx);
        w[c] = wv;
        sm += wv;
    }
    for (int o = 32; o; o >>= 1) sm += __shfl_xor(sm, o);
    if (lane == 0) red[4 + wave] = sm;
    __syncthreads();
    float inv = 1.f / (red[4] + red[5] + red[6] + red[7]);
    float a4[4] = {0.f, 0.f, 0.f, 0.f};
    for (int c = wave * (NC/4); c < (wave + 1) * (NC/4); c++) {
        float wv = w[c];
        const float* r = Rc + c * D;
        #pragma unroll
        for (int j = 0; j < 4; j++) { int dd = lane + 64*j; if (dd < D) a4[j] += wv * r[dd]; }
    }
    #pragma unroll
    for (int j = 0; j < 4; j++) { int dd = lane + 64*j; if (dd < D) part[wave][dd] = a4[j]; }
    __syncthreads();
    if (t < D) upd[b*D + t] = (part[0][t] + part[1][t] + part[2][t] + part[3][t]) * inv;
}

// ---------------- GK/GM (per graph) and SK/SM (per node type) ----------------
__global__ __launch_bounds__(256) void k_gkgm(const float* __restrict__ upd, const float* __restrict__ embS,
                                              const float* __restrict__ Wk, const float* __restrict__ bk,
                                              const float* __restrict__ Wm, const float* __restrict__ bm,
                                              float* GK, float* GM, float* SK, float* SM) {
    __shared__ float v[D];
    int bI = blockIdx.x, t = threadIdx.x;
    const float* in = (bI < BG) ? (upd + bI*D) : (embS + (bI - BG)*D);
    if (t < D) v[t] = in[t];
    __syncthreads();
    if (t < D) {
        float a1 = bk[t], a2 = bm[t];
        for (int k = 0; k < D; k++) {
            a1 += v[k] * Wk[(D + k)*D + t];
            a2 += v[k] * Wm[(D + k)*D + t];
        }
        if (bI < BG) { GK[bI*D + t] = a1; GM[bI*D + t] = a2; }
        else         { SK[(bI-BG)*D + t] = a1; SM[(bI-BG)*D + t] = a2; }
    }
}

// ---------------- weight packing: B-fragment order, bf16 hi/lo ----------------
__global__ __launch_bounds__(256) void k_packW(const float* __restrict__ Wk, const float* __restrict__ Wm,
                                               const float* __restrict__ Wq, const float* __restrict__ Wo1,
                                               const float* __restrict__ Wo2, short* __restrict__ Bpk) {
    int blk = blockIdx.x;                    // mat*91 + nt*7 + ks
    int mat = blk / (NTILES * KSTEPS);
    int rem = blk - mat * (NTILES * KSTEPS);
    int nt = rem / KSTEPS, ks = rem - nt * KSTEPS;
    const float* W = (mat == 0) ? Wk : (mat == 1) ? Wm : (mat == 2) ? Wq : (mat == 3) ? Wo1 : Wo2;
    int t = threadIdx.x;
    for (int idx = t; idx < 1024; idx += 256) {
        int split = idx >> 9;
        int lane = (idx & 511) >> 3;
        int j = idx & 7;
        int n = nt * 16 + (lane & 15);
        int k = ks * 32 + ((lane >> 4) << 3) + j;
        float v = (k < D && n < D) ? W[k * D + n] : 0.f;
        short h = bf_hi(v);
        short out = split ? bf_hi(v - bf_f(h)) : h;
        Bpk[(size_t)blk * 1024 + idx] = out;
    }
}

// ---------------- BN scale/shift precompute (keeps k_mmf LDS at 3 blocks/CU) ----------------
__global__ void k_bnprep(const float* __restrict__ bnacc, float invCnt,
                         const float* __restrict__ g, const float* __restrict__ bb,
                         float* __restrict__ sclg, float* __restrict__ sftg) {
    int t = threadIdx.x;
    if (t < D) {
        float m = bnacc[t] * invCnt;
        float var = bnacc[D + t] * invCnt - m * m;
        float rs = rsqrtf(var + 1e-5f);
        float s = rs * g[t];
        sclg[t] = s;
        sftg[t] = bb[t] - m * s;
    }
}

// ---------------- MFMA GEMM core (v3: compact LDS + zero-block tail + XOR swizzle) ----------------
// A in LDS: [strip 4][g 0..25][split 2][lanem^(g&15)] x bf16x8; slot 25 is a zero block.
// 53248 B -> 3 blocks/CU. Reads are branch-free (gc = min(g,25)).
__device__ __forceinline__ void stage_A(const float* __restrict__ A, int n0, short* Apk,
                                        int preop, const float* __restrict__ sclg,
                                        const float* __restrict__ sftg) {
    int t = threadIdx.x;
    bf16x8* Apk8 = (bf16x8*)Apk;
    if (t < 128) {
        int strip = t >> 5, split = (t >> 4) & 1, lanem = t & 15;
        bf16x8 z;
        #pragma unroll
        for (int j = 0; j < 8; j++) z[j] = 0;
        Apk8[((strip * GSLOT + NG) * 2 + split) * 16 + lanem] = z;
    }
    for (int f = t; f < 64 * NG; f += 256) {
        int r = f / NG, g = f - NG * r;
        const float* src = A + (size_t)(n0 + r) * D + g * 8;
        float v[8];
        float4 p0 = *(const float4*)src;
        float4 p1 = *(const float4*)(src + 4);
        v[0]=p0.x; v[1]=p0.y; v[2]=p0.z; v[3]=p0.w;
        v[4]=p1.x; v[5]=p1.y; v[6]=p1.z; v[7]=p1.w;
        if (preop) {
            float4 s0 = *(const float4*)&sclg[g*8];
            float4 s1 = *(const float4*)&sclg[g*8+4];
            float4 f0 = *(const float4*)&sftg[g*8];
            float4 f1 = *(const float4*)&sftg[g*8+4];
            v[0]=fmaxf(v[0]*s0.x+f0.x,0.f); v[1]=fmaxf(v[1]*s0.y+f0.y,0.f);
            v[2]=fmaxf(v[2]*s0.z+f0.z,0.f); v[3]=fmaxf(v[3]*s0.w+f0.w,0.f);
            v[4]=fmaxf(v[4]*s1.x+f1.x,0.f); v[5]=fmaxf(v[5]*s1.y+f1.y,0.f);
            v[6]=fmaxf(v[6]*s1.z+f1.z,0.f); v[7]=fmaxf(v[7]*s1.w+f1.w,0.f);
        }
        bf16x8 hi, lo;
        #pragma unroll
        for (int j = 0; j < 8; j++) {
            short h = bf_hi(v[j]);
            hi[j] = h;
            lo[j] = bf_hi(v[j] - bf_f(h));
        }
        int strip = r >> 4, lanem = r & 15;
        int sw = lanem ^ (g & 15);
        int base = (strip * GSLOT + g) * 2;
        Apk8[(base + 0) * 16 + sw] = hi;
        Apk8[(base + 1) * 16 + sw] = lo;
    }
}

__device__ __forceinline__ void mfma_strip(const short* Apk, const short* Bmat, int w, int lane,
                                           f32x4 acc[NTILES]) {
    const bf16x8* Apk8 = (const bf16x8*)Apk;
    const bf16x8* B8   = (const bf16x8*)Bmat;
    #pragma unroll
    for (int nt = 0; nt < NTILES; nt++) { acc[nt][0]=0.f; acc[nt][1]=0.f; acc[nt][2]=0.f; acc[nt][3]=0.f; }
    int quad = lane >> 4, lanem = lane & 15;
    for (int ks = 0; ks < KSTEPS; ks++) {
        int g = ks * 4 + quad;
        int gc = min(g, NG);                  // K-tail -> zero block, branch-free
        int sw = lanem ^ (gc & 15);
        int base = (w * GSLOT + gc) * 2;
        bf16x8 ah = Apk8[(base + 0) * 16 + sw];
        bf16x8 al = Apk8[(base + 1) * 16 + sw];
        #pragma unroll
        for (int nt = 0; nt < NTILES; nt++) {
            bf16x8 bh = B8[((nt * KSTEPS + ks) * 2 + 0) * 64 + lane];
            bf16x8 bl = B8[((nt * KSTEPS + ks) * 2 + 1) * 64 + lane];
            acc[nt] = __builtin_amdgcn_mfma_f32_16x16x32_bf16(al, bh, acc[nt], 0, 0, 0);
            acc[nt] = __builtin_amdgcn_mfma_f32_16x16x32_bf16(ah, bl, acc[nt], 0, 0, 0);
            acc[nt] = __builtin_amdgcn_mfma_f32_16x16x32_bf16(ah, bh, acc[nt], 0, 0, 0);
        }
    }
}

__device__ __forceinline__ void store_C(f32x4 acc[NTILES], float* __restrict__ C, int n0, int w, int lane,
                                        const float* __restrict__ bias, float postscale) {
    int colb = lane & 15, quad = lane >> 4;
    #pragma unroll
    for (int nt = 0; nt < NTILES; nt++) {
        int col = nt * 16 + colb;
        if (col < D) {
            float bj = bias ? bias[col] : 0.f;
            #pragma unroll
            for (int r = 0; r < 4; r++) {
                int row = n0 + w * 16 + quad * 4 + r;
                C[(size_t)row * D + col] = (acc[nt][r] + bj) * postscale;
            }
        }
    }
}

// ---------------- fused x @ {Wk[:D], Wm[:D], Wq}  (MFMA) ----------------
__global__ __launch_bounds__(256) void k_mmf3(const float* __restrict__ A, const short* __restrict__ Bpk,
                                              const float* __restrict__ bq,
                                              float* __restrict__ XK, float* __restrict__ XM, float* __restrict__ XQ) {
    __shared__ short Apk[4 * GSLOT * 2 * 16 * 8];   // 53248 B -> 3 blocks/CU
    int n0 = blockIdx.x * 64;
    stage_A(A, n0, Apk, 0, nullptr, nullptr);
    __syncthreads();
    int w = threadIdx.x >> 6, lane = threadIdx.x & 63;
    f32x4 acc[NTILES];
    const int matstride = NTILES * KSTEPS * 1024;   // shorts per mat = 91*1024
    mfma_strip(Apk, Bpk + 0 * matstride, w, lane, acc);
    store_C(acc, XK, n0, w, lane, nullptr, 1.f);
    mfma_strip(Apk, Bpk + 1 * matstride, w, lane, acc);
    store_C(acc, XM, n0, w, lane, nullptr, 1.f);
    mfma_strip(Apk, Bpk + 2 * matstride, w, lane, acc);
    store_C(acc, XQ, n0, w, lane, bq, 0.14142135623730950488f);
}

// ---------------- generic MFMA matmul, optional fused BN+relu preop (global scl/sft) ----------------
__global__ __launch_bounds__(256) void k_mmf(const float* __restrict__ A, const short* __restrict__ Bmat,
                                             const float* __restrict__ bias, float* __restrict__ C,
                                             int preop, const float* __restrict__ sclg,
                                             const float* __restrict__ sftg, float postscale) {
    __shared__ short Apk[4 * GSLOT * 2 * 16 * 8];
    int n0 = blockIdx.x * 64;
    stage_A(A, n0, Apk, preop, sclg, sftg);
    __syncthreads();
    int w = threadIdx.x >> 6, lane = threadIdx.x & 63;
    f32x4 acc[NTILES];
    mfma_strip(Apk, Bmat, w, lane, acc);
    store_C(acc, C, n0, w, lane, bias, postscale);
}

// ---------------- edge softmax, src-CSR, wave per node, no atomics ----------------
__global__ __launch_bounds__(256) void k_soft(const int* __restrict__ ei, const int* __restrict__ nt,
                                              const int* __restrict__ soff, const int* __restrict__ slist,
                                              const int* __restrict__ outdeg,
                                              const float* __restrict__ XQ, const float* __restrict__ XK,
                                              const float* __restrict__ GK, const float* __restrict__ SK,
                                              float* __restrict__ sc, float* __restrict__ scale) {
    int wave = threadIdx.x >> 6, lane = threadIdx.x & 63;
    int n = blockIdx.x * 4 + wave;
    if (n >= NN) return;
    float qv[4];
    #pragma unroll
    for (int j = 0; j < 4; j++) { int dd = lane + 64*j; qv[j] = (dd < D) ? XQ[(size_t)n*D + dd] : 0.f; }
    float den0 = 0.f, den1 = 0.f, den2 = 0.f, den3 = 0.f;
    {
        int tn = nt[n];
        float h0 = 0, h1 = 0, h2 = 0, h3 = 0;
        #pragma unroll
        for (int j = 0; j < 4; j++) {
            int dd = lane + 64*j;
            if (dd < D) {
                float p = qv[j] * (XK[(size_t)n*D + dd] + SK[tn*D + dd]);
                int hh = dd / DH;
                if (hh == 0) h0 += p; else if (hh == 1) h1 += p; else if (hh == 2) h2 += p; else h3 += p;
            }
        }
        for (int o = 32; o; o >>= 1) {
            h0 += __shfl_xor(h0, o); h1 += __shfl_xor(h1, o);
            h2 += __shfl_xor(h2, o); h3 += __shfl_xor(h3, o);
        }
        float e0 = __expf(h0), e1 = __expf(h1), e2 = __expf(h2), e3 = __expf(h3);
        den0 += e0; den1 += e1; den2 += e2; den3 += e3;
        if (lane < 4) {
            float v = (lane == 0) ? e0 : (lane == 1) ? e1 : (lane == 2) ? e2 : e3;
            sc[(size_t)(EE + n) * 4 + lane] = v;
        }
    }
    int beg = soff[n], end = soff[n + 1];
    for (int i = beg; i < end; i++) {
        int e = slist[i];
        int tail = ei[EE + e];
        int g = e >> 10;
        float h0 = 0, h1 = 0, h2 = 0, h3 = 0;
        #pragma unroll
        for (int j = 0; j < 4; j++) {
            int dd = lane + 64*j;
            if (dd < D) {
                float p = qv[j] * (XK[(size_t)tail*D + dd] + GK[g*D + dd]);
                int hh = dd / DH;
                if (hh == 0) h0 += p; else if (hh == 1) h1 += p; else if (hh == 2) h2 += p; else h3 += p;
            }
        }
        for (int o = 32; o; o >>= 1) {
            h0 += __shfl_xor(h0, o); h1 += __shfl_xor(h1, o);
            h2 += __shfl_xor(h2, o); h3 += __shfl_xor(h3, o);
        }
        float e0 = __expf(h0), e1 = __expf(h1), e2 = __expf(h2), e3 = __expf(h3);
        den0 += e0; den1 += e1; den2 += e2; den3 += e3;
        if (lane < 4) {
            float v = (lane == 0) ? e0 : (lane == 1) ? e1 : (lane == 2) ? e2 : e3;
            sc[(size_t)e * 4 + lane] = v;
        }
    }
    float cnt = (float)(outdeg[n] + 1);
    if (lane < 4) {
        float dn = (lane == 0) ? den0 : (lane == 1) ? den1 : (lane == 2) ? den2 : den3;
        scale[(size_t)n * 4 + lane] = cnt / dn;
    }
}

// ---------------- aggregation, dst-CSR, wave per node, no atomics ----------------
__global__ __launch_bounds__(256) void k_aggr(const int* __restrict__ ei, const int* __restrict__ nt,
                                              const int* __restrict__ doff, const int* __restrict__ dlist,
                                              const float* __restrict__ sc, const float* __restrict__ scale,
                                              const float* __restrict__ XM, const float* __restrict__ GM,
                                              const float* __restrict__ SM, float* __restrict__ aggr) {
    int wave = threadIdx.x >> 6, lane = threadIdx.x & 63;
    int n = blockIdx.x * 4 + wave;
    if (n >= NN) return;
    float acc[4] = {0.f, 0.f, 0.f, 0.f};
    {
        int tn = nt[n];
        float4 ss = *(const float4*)&sc[(size_t)(EE + n) * 4];
        float4 sl = *(const float4*)&scale[(size_t)n * 4];
        float a0 = ss.x * sl.x, a1 = ss.y * sl.y, a2 = ss.z * sl.z, a3 = ss.w * sl.w;
        #pragma unroll
        for (int j = 0; j < 4; j++) {
            int dd = lane + 64*j;
            if (dd < D) {
                float al = (dd < DH) ? a0 : (dd < 2*DH) ? a1 : (dd < 3*DH) ? a2 : a3;
                acc[j] += al * (XM[(size_t)n*D + dd] + SM[tn*D + dd]);
            }
        }
    }
    int beg = doff[n], end = doff[n + 1];
    for (int i = beg; i < end; i++) {
        int e = dlist[i];
        int s = ei[e];
        int g = e >> 10;
        float4 ss = *(const float4*)&sc[(size_t)e * 4];
        float4 sl = *(const float4*)&scale[(size_t)s * 4];
        float a0 = ss.x * sl.x, a1 = ss.y * sl.y, a2 = ss.z * sl.z, a3 = ss.w * sl.w;
        #pragma unroll
        for (int j = 0; j < 4; j++) {
            int dd = lane + 64*j;
            if (dd < D) {
                float al = (dd < DH) ? a0 : (dd < 2*DH) ? a1 : (dd < 3*DH) ? a2 : a3;
                acc[j] += al * (XM[(size_t)s*D + dd] + GM[g*D + dd]);
            }
        }
    }
    #pragma unroll
    for (int j = 0; j < 4; j++) {
        int dd = lane + 64*j;
        if (dd < D) aggr[(size_t)n*D + dd] = acc[j];
    }
}

// ---------------- column stats for final BN ----------------
__global__ __launch_bounds__(256) void k_colstats(const float* __restrict__ T1, float* bn3) {
    int t = threadIdx.x;
    if (t >= D) return;
    int r0 = blockIdx.x * 256;
    float s = 0.f, q = 0.f;
    for (int r = r0; r < r0 + 256; r++) {
        float v = T1[(size_t)r * D + t];
        s += v; q += v * v;
    }
    unsafeAtomicAdd(&bn3[t], s);
    unsafeAtomicAdd(&bn3[D + t], q);
}

extern "C" void kernel_launch(void* const* d_in, const int* in_sizes, int n_in,
                              void* d_out, int out_size, void* d_ws, size_t ws_size,
                              hipStream_t stream) {
    const float* x    = (const float*)d_in[0];
    const float* sent = (const float*)d_in[2];
    const float* We1  = (const float*)d_in[3];
    const float* be1  = (const float*)d_in[4];
    const float* ge1  = (const float*)d_in[5];
    const float* bte1 = (const float*)d_in[6];
    const float* We2  = (const float*)d_in[7];
    const float* be2  = (const float*)d_in[8];
    const float* Wa1  = (const float*)d_in[9];
    const float* ba1  = (const float*)d_in[10];
    const float* ga1  = (const float*)d_in[11];
    const float* bta1 = (const float*)d_in[12];
    const float* Wa2  = (const float*)d_in[13];
    const float* ba2  = (const float*)d_in[14];
    const float* Watt = (const float*)d_in[15];
    const float* Wk   = (const float*)d_in[16];
    const float* bk   = (const float*)d_in[17];
    const float* Wm   = (const float*)d_in[18];
    const float* bm   = (const float*)d_in[19];
    const float* Wq   = (const float*)d_in[20];
    const float* bq   = (const float*)d_in[21];
    const float* Wo1  = (const float*)d_in[22];
    const float* bo1  = (const float*)d_in[23];
    const float* go1  = (const float*)d_in[24];
    const float* bto1 = (const float*)d_in[25];
    const float* Wo2  = (const float*)d_in[26];
    const float* bo2  = (const float*)d_in[27];
    const int* ei = (const int*)d_in[28];
    const int* et = (const int*)d_in[29];
    const int* nt = (const int*)d_in[30];

    char* ws = (char*)d_ws;
    size_t off = 0;
    auto alloc = [&](size_t bytes) -> char* {
        char* p = ws + off;
        off = (off + bytes + 255) & ~(size_t)255;
        return p;
    };
    // ---- zeroed region ----
    int*   hist   = (int*)  alloc(NC * 4);
    int*   ntcnt  = (int*)  alloc(NTY * 4);
    float* bn1    = (float*)alloc(2 * D * 4);
    float* bn2    = (float*)alloc(2 * D * 4);
    float* bn3    = (float*)alloc(2 * D * 4);
    float* sumsxf = (float*)alloc(NE * D * 4);
    int*   outdeg = (int*)  alloc(NN * 4);
    int*   indeg  = (int*)  alloc(NN * 4);
    int*   hcnt   = (int*)  alloc((size_t)BG * NC * 4);   // per-graph combo histogram
    size_t zero_end = off;
    // ---- rest ----
    int* tcnt = (int*)alloc(NE * 4);
    int* soff_ = (int*)alloc((NN + 1) * 4);
    int* doff_ = (int*)alloc((NN + 1) * 4);
    int* scur = (int*)alloc(NN * 4);
    int* dcur = (int*)alloc(NN * 4);
    int* slist = (int*)alloc((size_t)EE * 4);
    int* dlist = (int*)alloc((size_t)EE * 4);
    short* Bpk  = (short*)alloc((size_t)5 * NTILES * KSTEPS * 1024 * 2);   // 5 mats, bf16 hi/lo packed
    float* sclg = (float*)alloc(D * 4);
    float* sftg = (float*)alloc(D * 4);
    float* h1v   = (float*)alloc((size_t)NCT * D * 4);
    float* embE  = (float*)alloc((size_t)NC * D * 4);
    float* embS  = (float*)alloc((size_t)NTY * D * 4);
    float* h2pre = (float*)alloc((size_t)NC * D * 4);
    float* Rc    = (float*)alloc((size_t)NC * D * 4);
    float* RcT   = (float*)alloc((size_t)D * NC * 4);
    float* upd   = (float*)alloc((size_t)BG * D * 4);
    float* GK    = (float*)alloc((size_t)BG * D * 4);
    float* GM    = (float*)alloc((size_t)BG * D * 4);
    float* SK    = (float*)alloc((size_t)NTY * D * 4);
    float* SM    = (float*)alloc((size_t)NTY * D * 4);
    float* sc    = (float*)alloc((size_t)EA * H * 4);
    float* XK    = (float*)alloc((size_t)NN * D * 4);
    float* XM    = (float*)alloc((size_t)NN * D * 4);
    float* XQ    = (float*)alloc((size_t)NN * D * 4);
    // aliases (liveness-checked):
    float* coef  = XK;            // dead before k_mmf3 writes XK
    float* scale = h1v;           // h1v dead before k_soft writes scale
    float* aggr  = XQ;            // XQ dead after k_soft
    float* T1    = XK;            // XK dead after k_soft

    const int matstride = NTILES * KSTEPS * 1024;   // shorts per packed mat

    hipMemsetAsync(ws, 0, zero_end, stream);
    hipMemsetAsync(coef, 0, (size_t)NN * NE * 4, stream);

    k_packW  <<<5 * NTILES * KSTEPS, 256, 0, stream>>>(Wk, Wm, Wq, Wo1, Wo2, Bpk);
    k_hist   <<<EE / 256, 256, 0, stream>>>(ei, et, nt, hist, outdeg, indeg, hcnt);
    k_ntcnt  <<<NN / 256, 256, 0, stream>>>(nt, ntcnt);
    k_coef   <<<EE / 256, 256, 0, stream>>>(ei, et, coef);
    k_tcnt   <<<1, 64, 0, stream>>>(hist, tcnt);
    k_scan   <<<1, 256, 0, stream>>>(outdeg, indeg, soff_, doff_, scur, dcur);
    k_scatter<<<EE / 256, 256, 0, stream>>>(ei, scur, dcur, slist, dlist);
    k_xfsum3 <<<256, 256, 0, stream>>>(x, coef, sumsxf);
    k_combos1<<<NCT, 256, 0, stream>>>(We1, be1, hist, ntcnt, h1v, bn1);
    k_combos2<<<NCT, 256, 0, stream>>>(h1v, bn1, ge1, bte1, We2, be2, embE, embS);
    k_combos3<<<NC, 256, 0, stream>>>(embE, sumsxf, tcnt, Wa1, ba1, hist, h2pre, bn2);
    k_combos4<<<NC, 256, 0, stream>>>(h2pre, bn2, ga1, bta1, Wa2, ba2, Rc, RcT);
    k_attn   <<<BG, 256, 0, stream>>>(sent, Watt, Rc, RcT, hcnt, upd);
    k_gkgm   <<<BG + NTY, 256, 0, stream>>>(upd, embS, Wk, bk, Wm, bm, GK, GM, SK, SM);
    k_mmf3   <<<NN / 64, 256, 0, stream>>>(x, Bpk, bq, XK, XM, XQ);
    k_soft   <<<NN / 4, 256, 0, stream>>>(ei, nt, soff_, slist, outdeg, XQ, XK, GK, SK, sc, scale);
    k_aggr   <<<NN / 4, 256, 0, stream>>>(ei, nt, doff_, dlist, sc, scale, XM, GM, SM, aggr);
    k_mmf    <<<NN / 64, 256, 0, stream>>>(aggr, Bpk + (size_t)3 * matstride, bo1, T1,
                                           0, nullptr, nullptr, 1.f);
    k_colstats<<<NN / 256, 256, 0, stream>>>(T1, bn3);
    k_bnprep <<<1, 256, 0, stream>>>(bn3, 1.f / (float)NN, go1, bto1, sclg, sftg);
    k_mmf    <<<NN / 64, 256, 0, stream>>>(T1, Bpk + (size_t)4 * matstride, bo2, (float*)d_out,
                                           1, sclg, sftg, 1.f);
}